// Round 1
// baseline (595.923 us; speedup 1.0000x reference)
//
#include <hip/hip_runtime.h>

typedef unsigned short u16;
typedef __attribute__((ext_vector_type(8))) __bf16 b8;
typedef __attribute__((ext_vector_type(4))) float f32x4;

#define T_SEQ 2048
#define NB 4
#define NH 16
#define HD 64
#define CEMB 1024
#define M_ROWS (NB * T_SEQ)  // 8192

__device__ __forceinline__ u16 f2bf(float f) {
  union { float f; unsigned int u; } v; v.f = f;
  unsigned int r = v.u + 0x7FFFu + ((v.u >> 16) & 1u);
  return (u16)(r >> 16);
}

__device__ __forceinline__ void gl_lds16(const u16* g, u16* l) {
  __builtin_amdgcn_global_load_lds(
      (const __attribute__((address_space(1))) unsigned int*)g,
      (__attribute__((address_space(3))) unsigned int*)l, 16, 0, 0);
}

// ---------------- convert fp32 -> bf16 (vectorized) ----------------
__global__ void k_convert(const float* __restrict__ in, u16* __restrict__ out, int n4) {
  int i = blockIdx.x * blockDim.x + threadIdx.x;
  int stride = gridDim.x * blockDim.x;
  for (; i < n4; i += stride) {
    float4 v = ((const float4*)in)[i];
    ushort4 o;
    o.x = f2bf(v.x); o.y = f2bf(v.y); o.z = f2bf(v.z); o.w = f2bf(v.w);
    ((ushort4*)out)[i] = o;
  }
}

// ------------- transpose + convert: W[K][N] fp32 -> Wt[N][K] bf16 -------------
__global__ __launch_bounds__(256) void k_transpose(const float* __restrict__ W,
                                                   u16* __restrict__ Wt, int K, int N) {
  __shared__ u16 t[64][65];
  int k0 = blockIdx.y * 64, n0 = blockIdx.x * 64;
  int tx = threadIdx.x & 63, ty = threadIdx.x >> 6;
  for (int i = ty; i < 64; i += 4)
    t[i][tx] = f2bf(W[(size_t)(k0 + i) * N + n0 + tx]);
  __syncthreads();
  for (int i = ty; i < 64; i += 4)
    Wt[(size_t)(n0 + i) * K + k0 + tx] = t[tx][i];
}

// ------------- bf16 GEMM, A[M][K] @ Bt[N][K]^T, m97 structure -------------
// MODE 0: qkv epilogue -> qk_bf [M][2048] (cols<2048) + vt [B*H*64][2048] (cols>=2048), +bias
// MODE 1: fp32 epilogue -> out_f [M][N], +bias
template <int MODE>
__global__ __launch_bounds__(256) void k_gemm(const u16* __restrict__ A, const u16* __restrict__ Bt,
                                              const float* __restrict__ bias,
                                              u16* __restrict__ out_bf, float* __restrict__ out_f,
                                              u16* __restrict__ vt, int M, int N, int K) {
  __shared__ u16 lds_a[128 * 32];
  __shared__ u16 lds_b[128 * 32];
  const int lane = threadIdx.x & 63;
  const int wave = threadIdx.x >> 6;
  const int wm = wave & 1, wn = wave >> 1;
  const int row0 = blockIdx.y * 128;
  const int col0 = blockIdx.x * 128;
  f32x4 acc[4][4] = {};
  const int lr = lane >> 2;         // 0..15: row within 16-row staging chunk
  const int lc = (lane & 3) * 8;    // col element offset (16B per lane)
  const u16* ga = A + (size_t)(row0 + wave * 32 + lr) * K + lc;
  const u16* gb = Bt + (size_t)(col0 + wave * 32 + lr) * K + lc;
  u16* la = lds_a + wave * 1024;
  u16* lb = lds_b + wave * 1024;
  const int fr = lane & 15, fk = (lane >> 4) * 8;

  for (int k0 = 0; k0 < K; k0 += 32) {
    __syncthreads();
    gl_lds16(ga + k0, la);
    gl_lds16(ga + 16 * K + k0, la + 512);
    gl_lds16(gb + k0, lb);
    gl_lds16(gb + 16 * K + k0, lb + 512);
    __syncthreads();
    b8 af[4], bfr[4];
#pragma unroll
    for (int i = 0; i < 4; ++i) af[i] = *(const b8*)&lds_a[(wm * 64 + i * 16 + fr) * 32 + fk];
#pragma unroll
    for (int i = 0; i < 4; ++i) bfr[i] = *(const b8*)&lds_b[(wn * 64 + i * 16 + fr) * 32 + fk];
#pragma unroll
    for (int mi = 0; mi < 4; ++mi)
#pragma unroll
      for (int ni = 0; ni < 4; ++ni)
        acc[mi][ni] = __builtin_amdgcn_mfma_f32_16x16x32_bf16(af[mi], bfr[ni], acc[mi][ni], 0, 0, 0);
  }

  const int fg = lane >> 4;
#pragma unroll
  for (int ni = 0; ni < 4; ++ni) {
    int col = col0 + wn * 64 + ni * 16 + fr;
    float bv = bias[col];
#pragma unroll
    for (int mi = 0; mi < 4; ++mi) {
#pragma unroll
      for (int r = 0; r < 4; ++r) {
        int row = row0 + wm * 64 + mi * 16 + fg * 4 + r;
        float v = acc[mi][ni][r] + bv;
        if (MODE == 0) {
          if (col < 2 * CEMB) {
            out_bf[(size_t)row * (2 * CEMB) + col] = f2bf(v);
          } else {
            int hd = col - 2 * CEMB;  // h*64 + d
            vt[((size_t)((row >> 11) * (NH * HD) + hd)) * T_SEQ + (row & (T_SEQ - 1))] = f2bf(v);
          }
        } else {
          out_f[(size_t)row * N + col] = v;
        }
      }
    }
  }
}

// ------------- causal flash attention -------------
// qk: [B*T][2048] bf16 (q cols 0..1023 = h*64+d, k cols 1024..2047)
// vt: [B*H*64][T] bf16 (V transposed)
// y : [B*T][1024] bf16
__global__ __launch_bounds__(256) void k_attn(const u16* __restrict__ qk,
                                              const u16* __restrict__ vt,
                                              u16* __restrict__ y) {
  __shared__ __align__(16) u16 pl_all[4][16 * 48];
  const int lane = threadIdx.x & 63;
  const int wave = threadIdx.x >> 6;
  const int bh = blockIdx.y;
  const int b = bh >> 4, h = bh & 15;
  const int q0 = blockIdx.x * 64 + wave * 16;  // this wave's 16 q-rows
  u16* pl = pl_all[wave];
  const int g = lane >> 4, c = lane & 15;

  // Q fragments hoisted (A-frag: row=lane&15, k=(lane>>4)*8+e)
  const u16* qrow = qk + (size_t)(b * T_SEQ + q0 + c) * (2 * CEMB) + h * HD + g * 8;
  b8 qf0 = *(const b8*)qrow;
  b8 qf1 = *(const b8*)(qrow + 32);

  float m[4] = {-3e38f, -3e38f, -3e38f, -3e38f};
  float l[4] = {0.f, 0.f, 0.f, 0.f};
  f32x4 o[4] = {};
  const int q_hi = q0 + 15;

  for (int k0 = 0; k0 <= q_hi; k0 += 32) {
    f32x4 s[2] = {};
#pragma unroll
    for (int n = 0; n < 2; ++n) {
      const u16* kp = qk + (size_t)(b * T_SEQ + k0 + n * 16 + c) * (2 * CEMB) + CEMB + h * HD + g * 8;
      s[n] = __builtin_amdgcn_mfma_f32_16x16x32_bf16(qf0, *(const b8*)kp, s[n], 0, 0, 0);
      s[n] = __builtin_amdgcn_mfma_f32_16x16x32_bf16(qf1, *(const b8*)(kp + 32), s[n], 0, 0, 0);
    }
    // scale + causal mask; S layout: row(q)=g*4+r, col(k)=n*16+c
    float sv[2][4], rm[4], ps[4];
#pragma unroll
    for (int r = 0; r < 4; ++r) {
      int row = q0 + g * 4 + r;
#pragma unroll
      for (int n = 0; n < 2; ++n) {
        int col = k0 + n * 16 + c;
        float xv = s[n][r] * 0.125f;
        sv[n][r] = (col > row) ? -3e38f : xv;
      }
      rm[r] = fmaxf(sv[0][r], sv[1][r]);
    }
#pragma unroll
    for (int off = 1; off < 16; off <<= 1)
#pragma unroll
      for (int r = 0; r < 4; ++r) rm[r] = fmaxf(rm[r], __shfl_xor(rm[r], off));

    u16 pb[2][4];
#pragma unroll
    for (int r = 0; r < 4; ++r) {
      float mn = fmaxf(m[r], rm[r]);
      float al = __expf(m[r] - mn);
      m[r] = mn;
      float p0 = __expf(sv[0][r] - mn);
      float p1 = __expf(sv[1][r] - mn);
      pb[0][r] = f2bf(p0);
      pb[1][r] = f2bf(p1);
      ps[r] = p0 + p1;
      l[r] *= al;
#pragma unroll
      for (int nt = 0; nt < 4; ++nt) o[nt][r] *= al;
    }
#pragma unroll
    for (int off = 1; off < 16; off <<= 1)
#pragma unroll
      for (int r = 0; r < 4; ++r) ps[r] += __shfl_xor(ps[r], off);
#pragma unroll
    for (int r = 0; r < 4; ++r) l[r] += ps[r];

    // P -> per-wave LDS tile [16 q][48-padded k]
#pragma unroll
    for (int n = 0; n < 2; ++n)
#pragma unroll
      for (int r = 0; r < 4; ++r) pl[(g * 4 + r) * 48 + n * 16 + c] = pb[n][r];
    asm volatile("s_waitcnt lgkmcnt(0)" ::: "memory");
    __builtin_amdgcn_sched_barrier(0);

    // PV: A-frag from P tile, B-frag from transposed V (contiguous tokens)
    b8 pa = *(const b8*)&pl[c * 48 + g * 8];
#pragma unroll
    for (int nt = 0; nt < 4; ++nt) {
      const b8 vb = *(const b8*)&vt[(size_t)(bh * HD + nt * 16 + c) * T_SEQ + k0 + g * 8];
      o[nt] = __builtin_amdgcn_mfma_f32_16x16x32_bf16(pa, vb, o[nt], 0, 0, 0);
    }
  }

#pragma unroll
  for (int r = 0; r < 4; ++r) {
    float inv = 1.0f / l[r];
#pragma unroll
    for (int nt = 0; nt < 4; ++nt)
      y[(size_t)(b * T_SEQ + q0 + g * 4 + r) * CEMB + h * HD + nt * 16 + c] = f2bf(o[nt][r] * inv);
  }
}

extern "C" void kernel_launch(void* const* d_in, const int* in_sizes, int n_in,
                              void* d_out, int out_size, void* d_ws, size_t ws_size,
                              hipStream_t stream) {
  const float* x = (const float*)d_in[0];       // [4,2048,1024]
  const float* W_attn = (const float*)d_in[1];  // [1024,3072]
  const float* b_attn = (const float*)d_in[2];  // [3072]
  const float* W_proj = (const float*)d_in[3];  // [1024,1024]
  const float* b_proj = (const float*)d_in[4];  // [1024]
  float* out = (float*)d_out;                   // [8192,1024] fp32

  char* ws = (char*)d_ws;
  u16* x_bf    = (u16*)(ws);                 // 16,777,216 B
  u16* wattn_t = (u16*)(ws + 16777216);      //  6,291,456 B
  u16* wproj_t = (u16*)(ws + 23068672);      //  2,097,152 B
  u16* qk_bf   = (u16*)(ws + 25165824);      // 33,554,432 B  [8192][2048]
  u16* vt      = (u16*)(ws + 58720256);      // 16,777,216 B  [4096][2048]
  u16* y_bf    = (u16*)(ws + 75497472);      // 16,777,216 B  -> total 92,274,688 B

  k_convert<<<2048, 256, 0, stream>>>(x, x_bf, (NB * T_SEQ * CEMB) / 4);
  k_transpose<<<dim3(3 * CEMB / 64, CEMB / 64), 256, 0, stream>>>(W_attn, wattn_t, CEMB, 3 * CEMB);
  k_transpose<<<dim3(CEMB / 64, CEMB / 64), 256, 0, stream>>>(W_proj, wproj_t, CEMB, CEMB);
  k_gemm<0><<<dim3(3 * CEMB / 128, M_ROWS / 128), 256, 0, stream>>>(
      x_bf, wattn_t, b_attn, qk_bf, nullptr, vt, M_ROWS, 3 * CEMB, CEMB);
  k_attn<<<dim3(T_SEQ / 64, NB * NH), 256, 0, stream>>>(qk_bf, vt, y_bf);
  k_gemm<1><<<dim3(CEMB / 128, M_ROWS / 128), 256, 0, stream>>>(
      y_bf, wproj_t, b_proj, nullptr, out, nullptr, M_ROWS, CEMB, CEMB);
}

// Round 2
// 314.421 us; speedup vs baseline: 1.8953x; 1.8953x over previous
//
#include <hip/hip_runtime.h>

typedef unsigned short u16;
typedef __attribute__((ext_vector_type(8))) __bf16 b8;
typedef __attribute__((ext_vector_type(4))) float f32x4;

#define T_SEQ 2048
#define NB 4
#define NH 16
#define HD 64
#define CEMB 1024
#define M_ROWS (NB * T_SEQ)  // 8192

__device__ __forceinline__ u16 f2bf(float f) {
  union { float f; unsigned int u; } v; v.f = f;
  unsigned int r = v.u + 0x7FFFu + ((v.u >> 16) & 1u);
  return (u16)(r >> 16);
}

__device__ __forceinline__ void gl_lds16(const u16* g, u16* l) {
  __builtin_amdgcn_global_load_lds(
      (const __attribute__((address_space(1))) unsigned int*)g,
      (__attribute__((address_space(3))) unsigned int*)l, 16, 0, 0);
}

// ---------------- convert fp32 -> bf16 (vectorized) ----------------
__global__ void k_convert(const float* __restrict__ in, u16* __restrict__ out, int n4) {
  int i = blockIdx.x * blockDim.x + threadIdx.x;
  int stride = gridDim.x * blockDim.x;
  for (; i < n4; i += stride) {
    float4 v = ((const float4*)in)[i];
    ushort4 o;
    o.x = f2bf(v.x); o.y = f2bf(v.y); o.z = f2bf(v.z); o.w = f2bf(v.w);
    ((ushort4*)out)[i] = o;
  }
}

// ------------- transpose + convert: W[K][N] fp32 -> Wt[N][K] bf16 -------------
__global__ __launch_bounds__(256) void k_transpose(const float* __restrict__ W,
                                                   u16* __restrict__ Wt, int K, int N) {
  __shared__ u16 t[64][65];
  int k0 = blockIdx.y * 64, n0 = blockIdx.x * 64;
  int tx = threadIdx.x & 63, ty = threadIdx.x >> 6;
  for (int i = ty; i < 64; i += 4)
    t[i][tx] = f2bf(W[(size_t)(k0 + i) * N + n0 + tx]);
  __syncthreads();
  for (int i = ty; i < 64; i += 4)
    Wt[(size_t)(n0 + i) * K + k0 + tx] = t[tx][i];
}

// ------------- bf16 GEMM, A[M][K] @ Bt[N][K]^T, m97 structure -------------
template <int MODE>
__global__ __launch_bounds__(256) void k_gemm(const u16* __restrict__ A, const u16* __restrict__ Bt,
                                              const float* __restrict__ bias,
                                              u16* __restrict__ out_bf, float* __restrict__ out_f,
                                              u16* __restrict__ vt, int M, int N, int K) {
  __shared__ u16 lds_a[128 * 32];
  __shared__ u16 lds_b[128 * 32];
  const int lane = threadIdx.x & 63;
  const int wave = threadIdx.x >> 6;
  const int wm = wave & 1, wn = wave >> 1;
  const int row0 = blockIdx.y * 128;
  const int col0 = blockIdx.x * 128;
  f32x4 acc[4][4] = {};
  const int lr = lane >> 2;
  const int lc = (lane & 3) * 8;
  const u16* ga = A + (size_t)(row0 + wave * 32 + lr) * K + lc;
  const u16* gb = Bt + (size_t)(col0 + wave * 32 + lr) * K + lc;
  u16* la = lds_a + wave * 1024;
  u16* lb = lds_b + wave * 1024;
  const int fr = lane & 15, fk = (lane >> 4) * 8;

  for (int k0 = 0; k0 < K; k0 += 32) {
    __syncthreads();
    gl_lds16(ga + k0, la);
    gl_lds16(ga + 16 * K + k0, la + 512);
    gl_lds16(gb + k0, lb);
    gl_lds16(gb + 16 * K + k0, lb + 512);
    __syncthreads();
    b8 af[4], bfr[4];
#pragma unroll
    for (int i = 0; i < 4; ++i) af[i] = *(const b8*)&lds_a[(wm * 64 + i * 16 + fr) * 32 + fk];
#pragma unroll
    for (int i = 0; i < 4; ++i) bfr[i] = *(const b8*)&lds_b[(wn * 64 + i * 16 + fr) * 32 + fk];
#pragma unroll
    for (int mi = 0; mi < 4; ++mi)
#pragma unroll
      for (int ni = 0; ni < 4; ++ni)
        acc[mi][ni] = __builtin_amdgcn_mfma_f32_16x16x32_bf16(af[mi], bfr[ni], acc[mi][ni], 0, 0, 0);
  }

  const int fg = lane >> 4;
#pragma unroll
  for (int ni = 0; ni < 4; ++ni) {
    int col = col0 + wn * 64 + ni * 16 + fr;
    float bv = bias[col];
#pragma unroll
    for (int mi = 0; mi < 4; ++mi) {
#pragma unroll
      for (int r = 0; r < 4; ++r) {
        int row = row0 + wm * 64 + mi * 16 + fg * 4 + r;
        float v = acc[mi][ni][r] + bv;
        if (MODE == 0) {
          if (col < 2 * CEMB) {
            out_bf[(size_t)row * (2 * CEMB) + col] = f2bf(v);
          } else {
            int hd = col - 2 * CEMB;
            vt[((size_t)((row >> 11) * (NH * HD) + hd)) * T_SEQ + (row & (T_SEQ - 1))] = f2bf(v);
          }
        } else {
          out_f[(size_t)row * N + col] = v;
        }
      }
    }
  }
}

// ------------- causal flash attention, staged KV (KVBLK=64, dbuf, swizzled) -------------
// qk: [B*T][2048] bf16 (q cols 0..1023 = h*64+d, k cols 1024..2047)
// vtg: [B*H*64][T] bf16 (V transposed)
// y : [B*T][1024] bf16
__global__ __launch_bounds__(256) void k_attn(const u16* __restrict__ qk,
                                              const u16* __restrict__ vtg,
                                              u16* __restrict__ y) {
  // LDS: K tiles 2x8KB, V tiles 2x8KB, P per-wave 4x2KB = 40960 B
  __shared__ __align__(16) u16 kt_s[2][64 * 64];
  __shared__ __align__(16) u16 vt_s[2][64 * 64];
  __shared__ __align__(16) u16 pl_s[4][16 * 64];

  const int lane = threadIdx.x & 63;
  const int wave = threadIdx.x >> 6;
  const int tid = threadIdx.x;
  const int g = lane >> 4, c = lane & 15;

  // XCD-chunked, work-descending schedule: 2048 blocks, 8 XCDs, 8 heads/XCD
  const int orig = blockIdx.x;
  const int fid = (orig & 7) * 256 + (orig >> 3);  // chunked per-XCD id
  const int bh = fid >> 5;                          // 0..63
  const int tile = 31 - (fid & 31);                 // long blocks dispatch first
  const int b = bh >> 4, h = bh & 15;
  const int q0w = tile * 64 + wave * 16;            // this wave's 16 q-rows

  u16* pl = pl_s[wave];

  // Q fragments hoisted (A-frag: row=lane&15, k=(lane>>4)*8+e)
  const u16* qrow = qk + (size_t)(b * T_SEQ + q0w + c) * (2 * CEMB) + h * HD + g * 8;
  const b8 qf0 = *(const b8*)qrow;
  const b8 qf1 = *(const b8*)(qrow + 32);

  // staging source addressing (pre-swizzled global source, linear LDS dest)
  const int srow = tid >> 3;                        // 0..31 (call0), +32 (call1)
  const int scc = (tid & 7) ^ (srow & 7);           // swizzled source chunk
  const u16* ksrc0 = qk + ((size_t)(b * T_SEQ) + srow) * (2 * CEMB) + CEMB + h * HD + scc * 8;
  const u16* vsrc0 = vtg + ((size_t)(bh * HD) + srow) * T_SEQ + scc * 8;

  float m[4] = {-3e38f, -3e38f, -3e38f, -3e38f};
  float l[4] = {0.f, 0.f, 0.f, 0.f};
  f32x4 o[4] = {};

  const int nt_tiles = tile + 1;

#define STAGE(t, bb)                                                    \
  {                                                                     \
    const u16* ks_ = ksrc0 + (size_t)(t) * 64 * (2 * CEMB);             \
    const u16* vs_ = vsrc0 + (t) * 64;                                  \
    gl_lds16(ks_, &kt_s[bb][wave * 512]);                               \
    gl_lds16(ks_ + 32 * (2 * CEMB), &kt_s[bb][wave * 512 + 2048]);      \
    gl_lds16(vs_, &vt_s[bb][wave * 512]);                               \
    gl_lds16(vs_ + 32 * T_SEQ, &vt_s[bb][wave * 512 + 2048]);           \
  }

  STAGE(0, 0);
  __syncthreads();

  int cur = 0;
  for (int t = 0; t < nt_tiles; ++t) {
    if (t + 1 < nt_tiles) STAGE(t + 1, cur ^ 1);
    const bool diag = (t == nt_tiles - 1);
    const u16* kt = kt_s[cur];
    const u16* vtl = vt_s[cur];
    const int k0 = t * 64;

    // QK^T: s[n] over 4 column-subtiles of 16; skip n>wave on diagonal tile
    f32x4 s[4] = {{0.f,0.f,0.f,0.f},{0.f,0.f,0.f,0.f},{0.f,0.f,0.f,0.f},{0.f,0.f,0.f,0.f}};
    const int nhi = diag ? wave : 3;
    for (int n = 0; n <= nhi; ++n) {
      const b8 kf0 = *(const b8*)&kt[(n * 16 + c) * 64 + ((g ^ (c & 7)) << 3)];
      const b8 kf1 = *(const b8*)&kt[(n * 16 + c) * 64 + (((4 + g) ^ (c & 7)) << 3)];
      s[n] = __builtin_amdgcn_mfma_f32_16x16x32_bf16(qf0, kf0, s[n], 0, 0, 0);
      s[n] = __builtin_amdgcn_mfma_f32_16x16x32_bf16(qf1, kf1, s[n], 0, 0, 0);
    }

    // scale + causal mask; S layout: row(q)=g*4+r, col(k)=n*16+c
    float sv[4][4], rm[4], ps[4];
#pragma unroll
    for (int r = 0; r < 4; ++r) {
      int row = q0w + g * 4 + r;
#pragma unroll
      for (int n = 0; n < 4; ++n) {
        int col = k0 + n * 16 + c;
        float xv = s[n][r] * 0.125f;
        sv[n][r] = (diag && col > row) ? -3e38f : xv;
      }
      rm[r] = fmaxf(fmaxf(sv[0][r], sv[1][r]), fmaxf(sv[2][r], sv[3][r]));
    }
#pragma unroll
    for (int off = 1; off < 16; off <<= 1)
#pragma unroll
      for (int r = 0; r < 4; ++r) rm[r] = fmaxf(rm[r], __shfl_xor(rm[r], off));

    u16 pb[4][4];
#pragma unroll
    for (int r = 0; r < 4; ++r) {
      float mn = fmaxf(m[r], rm[r]);
      float al = __expf(m[r] - mn);
      m[r] = mn;
      float psum = 0.f;
#pragma unroll
      for (int n = 0; n < 4; ++n) {
        float p = __expf(sv[n][r] - mn);
        pb[n][r] = f2bf(p);
        psum += p;
      }
      ps[r] = psum;
      l[r] *= al;
#pragma unroll
      for (int nt = 0; nt < 4; ++nt) o[nt][r] *= al;
    }
#pragma unroll
    for (int off = 1; off < 16; off <<= 1)
#pragma unroll
      for (int r = 0; r < 4; ++r) ps[r] += __shfl_xor(ps[r], off);
#pragma unroll
    for (int r = 0; r < 4; ++r) l[r] += ps[r];

    // P -> per-wave swizzled LDS tile [16 q][64 k], elem ^= ((q&7)<<3)
#pragma unroll
    for (int n = 0; n < 4; ++n)
#pragma unroll
      for (int r = 0; r < 4; ++r) {
        int q = g * 4 + r;
        pl[q * 64 + ((n * 16 + c) ^ ((q & 7) << 3))] = pb[n][r];
      }

    // PV: A-frag from swizzled P tile, B-frag from swizzled V tile
#pragma unroll
    for (int ks = 0; ks < 2; ++ks) {
      const b8 pa = *(const b8*)&pl[c * 64 + ((ks * 32 + g * 8) ^ ((c & 7) << 3))];
#pragma unroll
      for (int nt = 0; nt < 4; ++nt) {
        const b8 vb = *(const b8*)&vtl[(nt * 16 + c) * 64 + (((ks * 4 + g) ^ (c & 7)) << 3)];
        o[nt] = __builtin_amdgcn_mfma_f32_16x16x32_bf16(pa, vb, o[nt], 0, 0, 0);
      }
    }

    __syncthreads();
    cur ^= 1;
  }
#undef STAGE

#pragma unroll
  for (int r = 0; r < 4; ++r) {
    float inv = 1.0f / l[r];
#pragma unroll
    for (int nt = 0; nt < 4; ++nt)
      y[(size_t)(b * T_SEQ + q0w + g * 4 + r) * CEMB + h * HD + nt * 16 + c] = f2bf(o[nt][r] * inv);
  }
}

extern "C" void kernel_launch(void* const* d_in, const int* in_sizes, int n_in,
                              void* d_out, int out_size, void* d_ws, size_t ws_size,
                              hipStream_t stream) {
  const float* x = (const float*)d_in[0];
  const float* W_attn = (const float*)d_in[1];
  const float* b_attn = (const float*)d_in[2];
  const float* W_proj = (const float*)d_in[3];
  const float* b_proj = (const float*)d_in[4];
  float* out = (float*)d_out;

  char* ws = (char*)d_ws;
  u16* x_bf    = (u16*)(ws);
  u16* wattn_t = (u16*)(ws + 16777216);
  u16* wproj_t = (u16*)(ws + 23068672);
  u16* qk_bf   = (u16*)(ws + 25165824);
  u16* vt      = (u16*)(ws + 58720256);
  u16* y_bf    = (u16*)(ws + 75497472);

  k_convert<<<2048, 256, 0, stream>>>(x, x_bf, (NB * T_SEQ * CEMB) / 4);
  k_transpose<<<dim3(3 * CEMB / 64, CEMB / 64), 256, 0, stream>>>(W_attn, wattn_t, CEMB, 3 * CEMB);
  k_transpose<<<dim3(CEMB / 64, CEMB / 64), 256, 0, stream>>>(W_proj, wproj_t, CEMB, CEMB);
  k_gemm<0><<<dim3(3 * CEMB / 128, M_ROWS / 128), 256, 0, stream>>>(
      x_bf, wattn_t, b_attn, qk_bf, nullptr, vt, M_ROWS, 3 * CEMB, CEMB);
  k_attn<<<2048, 256, 0, stream>>>(qk_bf, vt, y_bf);
  k_gemm<1><<<dim3(CEMB / 128, M_ROWS / 128), 256, 0, stream>>>(
      y_bf, wproj_t, b_proj, nullptr, out, nullptr, M_ROWS, CEMB, CEMB);
}

// Round 3
// 258.900 us; speedup vs baseline: 2.3017x; 1.2144x over previous
//
#include <hip/hip_runtime.h>

typedef unsigned short u16;
typedef __attribute__((ext_vector_type(8))) __bf16 b8;
typedef __attribute__((ext_vector_type(4))) float f32x4;

#define T_SEQ 2048
#define NB 4
#define NH 16
#define HD 64
#define CEMB 1024
#define M_ROWS (NB * T_SEQ)  // 8192
// 0.125 * log2(e): folds softmax scale AND exp->exp2 conversion into Q
#define Q_PRESCALE 0.18033688011112042f

__device__ __forceinline__ u16 f2bf(float f) {
  union { float f; unsigned int u; } v; v.f = f;
  unsigned int r = v.u + 0x7FFFu + ((v.u >> 16) & 1u);
  return (u16)(r >> 16);
}

__device__ __forceinline__ void gl_lds16(const u16* g, u16* l) {
  __builtin_amdgcn_global_load_lds(
      (const __attribute__((address_space(1))) unsigned int*)g,
      (__attribute__((address_space(3))) unsigned int*)l, 16, 0, 0);
}

// ---------------- convert fp32 -> bf16 (vectorized) ----------------
__global__ void k_convert(const float* __restrict__ in, u16* __restrict__ out, int n4) {
  int i = blockIdx.x * blockDim.x + threadIdx.x;
  int stride = gridDim.x * blockDim.x;
  for (; i < n4; i += stride) {
    float4 v = ((const float4*)in)[i];
    ushort4 o;
    o.x = f2bf(v.x); o.y = f2bf(v.y); o.z = f2bf(v.z); o.w = f2bf(v.w);
    ((ushort4*)out)[i] = o;
  }
}

// ------------- transpose + convert: W[K][N] fp32 -> Wt[N][K] bf16 -------------
__global__ __launch_bounds__(256) void k_transpose(const float* __restrict__ W,
                                                   u16* __restrict__ Wt, int K, int N) {
  __shared__ u16 t[64][65];
  int k0 = blockIdx.y * 64, n0 = blockIdx.x * 64;
  int tx = threadIdx.x & 63, ty = threadIdx.x >> 6;
  for (int i = ty; i < 64; i += 4)
    t[i][tx] = f2bf(W[(size_t)(k0 + i) * N + n0 + tx]);
  __syncthreads();
  for (int i = ty; i < 64; i += 4)
    Wt[(size_t)(n0 + i) * K + k0 + tx] = t[tx][i];
}

// ------------- bf16 GEMM, A[M][K] @ Bt[N][K]^T, m97 structure -------------
template <int MODE>
__global__ __launch_bounds__(256) void k_gemm(const u16* __restrict__ A, const u16* __restrict__ Bt,
                                              const float* __restrict__ bias,
                                              u16* __restrict__ out_bf, float* __restrict__ out_f,
                                              u16* __restrict__ vt, int M, int N, int K) {
  __shared__ u16 lds_a[128 * 32];
  __shared__ u16 lds_b[128 * 32];
  const int lane = threadIdx.x & 63;
  const int wave = threadIdx.x >> 6;
  const int wm = wave & 1, wn = wave >> 1;
  const int row0 = blockIdx.y * 128;
  const int col0 = blockIdx.x * 128;
  f32x4 acc[4][4] = {};
  const int lr = lane >> 2;
  const int lc = (lane & 3) * 8;
  const u16* ga = A + (size_t)(row0 + wave * 32 + lr) * K + lc;
  const u16* gb = Bt + (size_t)(col0 + wave * 32 + lr) * K + lc;
  u16* la = lds_a + wave * 1024;
  u16* lb = lds_b + wave * 1024;
  const int fr = lane & 15, fk = (lane >> 4) * 8;

  for (int k0 = 0; k0 < K; k0 += 32) {
    __syncthreads();
    gl_lds16(ga + k0, la);
    gl_lds16(ga + 16 * K + k0, la + 512);
    gl_lds16(gb + k0, lb);
    gl_lds16(gb + 16 * K + k0, lb + 512);
    __syncthreads();
    b8 af[4], bfr[4];
#pragma unroll
    for (int i = 0; i < 4; ++i) af[i] = *(const b8*)&lds_a[(wm * 64 + i * 16 + fr) * 32 + fk];
#pragma unroll
    for (int i = 0; i < 4; ++i) bfr[i] = *(const b8*)&lds_b[(wn * 64 + i * 16 + fr) * 32 + fk];
#pragma unroll
    for (int mi = 0; mi < 4; ++mi)
#pragma unroll
      for (int ni = 0; ni < 4; ++ni)
        acc[mi][ni] = __builtin_amdgcn_mfma_f32_16x16x32_bf16(af[mi], bfr[ni], acc[mi][ni], 0, 0, 0);
  }

  const int fg = lane >> 4;
#pragma unroll
  for (int ni = 0; ni < 4; ++ni) {
    int col = col0 + wn * 64 + ni * 16 + fr;
    float bv = bias[col];
#pragma unroll
    for (int mi = 0; mi < 4; ++mi) {
#pragma unroll
      for (int r = 0; r < 4; ++r) {
        int row = row0 + wm * 64 + mi * 16 + fg * 4 + r;
        float v = acc[mi][ni][r] + bv;
        if (MODE == 0) {
          if (col < CEMB) {
            // Q: pre-scale by 0.125*log2(e) so attention scores are in log2 units
            out_bf[(size_t)row * (2 * CEMB) + col] = f2bf(v * Q_PRESCALE);
          } else if (col < 2 * CEMB) {
            out_bf[(size_t)row * (2 * CEMB) + col] = f2bf(v);
          } else {
            int hd = col - 2 * CEMB;
            vt[((size_t)((row >> 11) * (NH * HD) + hd)) * T_SEQ + (row & (T_SEQ - 1))] = f2bf(v);
          }
        } else {
          out_f[(size_t)row * N + col] = v;
        }
      }
    }
  }
}

// ------------- causal flash attention, staged KV (KVBLK=64, dbuf, swizzled) -------------
// qk: [B*T][2048] bf16 (q cols 0..1023 pre-scaled, k cols 1024..2047)
// vtg: [B*H*64][T] bf16 (V transposed)
// y : [B*T][1024] bf16
__global__ __launch_bounds__(256) void k_attn(const u16* __restrict__ qk,
                                              const u16* __restrict__ vtg,
                                              u16* __restrict__ y) {
  __shared__ __align__(16) u16 kt_s[2][64 * 64];
  __shared__ __align__(16) u16 vt_s[2][64 * 64];
  __shared__ __align__(16) u16 pl_s[4][16 * 64];

  const int lane = threadIdx.x & 63;
  const int wave = threadIdx.x >> 6;
  const int tid = threadIdx.x;
  const int g = lane >> 4, c = lane & 15;

  // Balanced XCD-chunked schedule: XCD x runs heads 8x..8x+7 (one per round);
  // within a round, CU j gets tile (31-j) or (j) alternating -> every CU's
  // total work is exactly sum of 4 pairs (t, 31-t) = 132 iterations.
  const int orig = blockIdx.x;
  const int xcd = orig & 7;
  const int s_in = orig >> 3;       // 0..255 within XCD
  const int cu = s_in & 31;
  const int rr = s_in >> 5;         // 0..7 (head round)
  const int bh = xcd * 8 + rr;
  const int tile = (rr & 1) ? cu : (31 - cu);
  const int b = bh >> 4, h = bh & 15;
  const int q0w = tile * 64 + wave * 16;

  u16* pl = pl_s[wave];

  // Q fragments hoisted (A-frag: row=lane&15, k=(lane>>4)*8+e)
  const u16* qrow = qk + (size_t)(b * T_SEQ + q0w + c) * (2 * CEMB) + h * HD + g * 8;
  const b8 qf0 = *(const b8*)qrow;
  const b8 qf1 = *(const b8*)(qrow + 32);

  // constant ones B-frag: lanes with c==0 hold row of ones -> col 0 of MFMA
  // output = row-sum of P (accumulates the softmax denominator in-pipe)
  b8 ones_frag;
#pragma unroll
  for (int e = 0; e < 8; ++e) ones_frag[e] = (c == 0) ? (__bf16)1.0f : (__bf16)0.0f;

  // staging source addressing (pre-swizzled global source, linear LDS dest)
  const int srow = tid >> 3;
  const int scc = (tid & 7) ^ (srow & 7);
  const u16* ksrc0 = qk + ((size_t)(b * T_SEQ) + srow) * (2 * CEMB) + CEMB + h * HD + scc * 8;
  const u16* vsrc0 = vtg + ((size_t)(bh * HD) + srow) * T_SEQ + scc * 8;

  float m[4] = {-3e38f, -3e38f, -3e38f, -3e38f};
  f32x4 o[4] = {};
  f32x4 o4 = {0.f, 0.f, 0.f, 0.f};  // softmax denominator accumulator (col 0)

  const int nt_tiles = tile + 1;

#define STAGE(t, bb)                                                    \
  {                                                                     \
    const u16* ks_ = ksrc0 + (size_t)(t) * 64 * (2 * CEMB);             \
    const u16* vs_ = vsrc0 + (t) * 64;                                  \
    gl_lds16(ks_, &kt_s[bb][wave * 512]);                               \
    gl_lds16(ks_ + 32 * (2 * CEMB), &kt_s[bb][wave * 512 + 2048]);      \
    gl_lds16(vs_, &vt_s[bb][wave * 512]);                               \
    gl_lds16(vs_ + 32 * T_SEQ, &vt_s[bb][wave * 512 + 2048]);           \
  }

  STAGE(0, 0);
  __syncthreads();

  int cur = 0;
  for (int t = 0; t < nt_tiles; ++t) {
    if (t + 1 < nt_tiles) STAGE(t + 1, cur ^ 1);
    const bool diag = (t == nt_tiles - 1);
    const u16* kt = kt_s[cur];
    const u16* vtl = vt_s[cur];
    const int k0 = t * 64;

    f32x4 s[4] = {{0.f,0.f,0.f,0.f},{0.f,0.f,0.f,0.f},{0.f,0.f,0.f,0.f},{0.f,0.f,0.f,0.f}};
#pragma unroll
    for (int n = 0; n < 4; ++n) {
      if (!diag || n <= wave) {
        const b8 kf0 = *(const b8*)&kt[(n * 16 + c) * 64 + ((g ^ (c & 7)) << 3)];
        const b8 kf1 = *(const b8*)&kt[(n * 16 + c) * 64 + (((4 + g) ^ (c & 7)) << 3)];
        s[n] = __builtin_amdgcn_mfma_f32_16x16x32_bf16(qf0, kf0, s[n], 0, 0, 0);
        s[n] = __builtin_amdgcn_mfma_f32_16x16x32_bf16(qf1, kf1, s[n], 0, 0, 0);
      }
    }

    // causal mask (diagonal tile only; uniform branch)
    if (diag) {
#pragma unroll
      for (int r = 0; r < 4; ++r) {
        int row = q0w + g * 4 + r;
#pragma unroll
        for (int n = 0; n < 4; ++n) {
          int col = k0 + n * 16 + c;
          if (col > row) s[n][r] = -3e38f;
        }
      }
    }

    // row max (scores already in log2 units)
    float rm[4];
#pragma unroll
    for (int r = 0; r < 4; ++r)
      rm[r] = fmaxf(fmaxf(s[0][r], s[1][r]), fmaxf(s[2][r], s[3][r]));
#pragma unroll
    for (int off = 1; off < 16; off <<= 1)
#pragma unroll
      for (int r = 0; r < 4; ++r) rm[r] = fmaxf(rm[r], __shfl_xor(rm[r], off));

    // defer-max: only rescale when some row max grew by > 8 (P bounded by 2^8)
    bool ok = (rm[0] <= m[0] + 8.0f) && (rm[1] <= m[1] + 8.0f) &&
              (rm[2] <= m[2] + 8.0f) && (rm[3] <= m[3] + 8.0f);
    if (!__all(ok)) {
#pragma unroll
      for (int r = 0; r < 4; ++r) {
        float mn = fmaxf(m[r], rm[r]);
        float al = __builtin_amdgcn_exp2f(m[r] - mn);
        m[r] = mn;
#pragma unroll
        for (int nt = 0; nt < 4; ++nt) o[nt][r] *= al;
        o4[r] *= al;
      }
    }

    // P = exp2(s - m), convert to bf16, store to swizzled per-wave LDS tile
#pragma unroll
    for (int n = 0; n < 4; ++n)
#pragma unroll
      for (int r = 0; r < 4; ++r) {
        float p = __builtin_amdgcn_exp2f(s[n][r] - m[r]);
        __bf16 pbv = (__bf16)p;
        int q = g * 4 + r;
        pl[q * 64 + ((n * 16 + c) ^ ((q & 7) << 3))] = *(u16*)&pbv;
      }

    // PV: A-frag from swizzled P tile, B-frag from swizzled V tile.
    // Extra MFMA with constant ones B-frag accumulates row-sums into o4 col 0.
#pragma unroll
    for (int ks = 0; ks < 2; ++ks) {
      const b8 pa = *(const b8*)&pl[c * 64 + ((ks * 32 + g * 8) ^ ((c & 7) << 3))];
      o4 = __builtin_amdgcn_mfma_f32_16x16x32_bf16(pa, ones_frag, o4, 0, 0, 0);
#pragma unroll
      for (int nt = 0; nt < 4; ++nt) {
        const b8 vb = *(const b8*)&vtl[(nt * 16 + c) * 64 + (((ks * 4 + g) ^ (c & 7)) << 3)];
        o[nt] = __builtin_amdgcn_mfma_f32_16x16x32_bf16(pa, vb, o[nt], 0, 0, 0);
      }
    }

    __syncthreads();
    cur ^= 1;
  }
#undef STAGE

  // denominator lives in col 0 (lanes with c==0); broadcast within g-group
#pragma unroll
  for (int r = 0; r < 4; ++r) {
    float lr = __shfl(o4[r], lane & 48);
    float inv = 1.0f / lr;
#pragma unroll
    for (int nt = 0; nt < 4; ++nt) {
      __bf16 ov = (__bf16)(o[nt][r] * inv);
      y[(size_t)(b * T_SEQ + q0w + g * 4 + r) * CEMB + h * HD + nt * 16 + c] = *(u16*)&ov;
    }
  }
}

extern "C" void kernel_launch(void* const* d_in, const int* in_sizes, int n_in,
                              void* d_out, int out_size, void* d_ws, size_t ws_size,
                              hipStream_t stream) {
  const float* x = (const float*)d_in[0];
  const float* W_attn = (const float*)d_in[1];
  const float* b_attn = (const float*)d_in[2];
  const float* W_proj = (const float*)d_in[3];
  const float* b_proj = (const float*)d_in[4];
  float* out = (float*)d_out;

  char* ws = (char*)d_ws;
  u16* x_bf    = (u16*)(ws);
  u16* wattn_t = (u16*)(ws + 16777216);
  u16* wproj_t = (u16*)(ws + 23068672);
  u16* qk_bf   = (u16*)(ws + 25165824);
  u16* vt      = (u16*)(ws + 58720256);
  u16* y_bf    = (u16*)(ws + 75497472);

  k_convert<<<2048, 256, 0, stream>>>(x, x_bf, (NB * T_SEQ * CEMB) / 4);
  k_transpose<<<dim3(3 * CEMB / 64, CEMB / 64), 256, 0, stream>>>(W_attn, wattn_t, CEMB, 3 * CEMB);
  k_transpose<<<dim3(CEMB / 64, CEMB / 64), 256, 0, stream>>>(W_proj, wproj_t, CEMB, CEMB);
  k_gemm<0><<<dim3(3 * CEMB / 128, M_ROWS / 128), 256, 0, stream>>>(
      x_bf, wattn_t, b_attn, qk_bf, nullptr, vt, M_ROWS, 3 * CEMB, CEMB);
  k_attn<<<2048, 256, 0, stream>>>(qk_bf, vt, y_bf);
  k_gemm<1><<<dim3(CEMB / 128, M_ROWS / 128), 256, 0, stream>>>(
      y_bf, wproj_t, b_proj, nullptr, out, nullptr, M_ROWS, CEMB, CEMB);
}

// Round 4
// 242.069 us; speedup vs baseline: 2.4618x; 1.0695x over previous
//
#include <hip/hip_runtime.h>

typedef unsigned short u16;
typedef unsigned int u32;
typedef unsigned long long u64;
typedef __attribute__((ext_vector_type(8))) __bf16 b8;
typedef __attribute__((ext_vector_type(4))) float f32x4;

#define T_SEQ 2048
#define NB 4
#define NH 16
#define HD 64
#define CEMB 1024
#define M_ROWS (NB * T_SEQ)  // 8192
// 0.125 * log2(e): folds softmax scale AND exp->exp2 conversion into Q
#define Q_PRESCALE 0.18033688011112042f

__device__ __forceinline__ u16 f2bf(float f) {
  union { float f; unsigned int u; } v; v.f = f;
  unsigned int r = v.u + 0x7FFFu + ((v.u >> 16) & 1u);
  return (u16)(r >> 16);
}

__device__ __forceinline__ u32 pk2bf(float a, float b) {
  __bf16 x = (__bf16)a, y = (__bf16)b;
  return (u32)*(u16*)&x | ((u32)*(u16*)&y << 16);
}

__device__ __forceinline__ void gl_lds16(const u16* g, u16* l) {
  __builtin_amdgcn_global_load_lds(
      (const __attribute__((address_space(1))) unsigned int*)g,
      (__attribute__((address_space(3))) unsigned int*)l, 16, 0, 0);
}

// ---------------- convert fp32 -> bf16 (vectorized) ----------------
__global__ void k_convert(const float* __restrict__ in, u16* __restrict__ out, int n4) {
  int i = blockIdx.x * blockDim.x + threadIdx.x;
  int stride = gridDim.x * blockDim.x;
  for (; i < n4; i += stride) {
    float4 v = ((const float4*)in)[i];
    ushort4 o;
    o.x = f2bf(v.x); o.y = f2bf(v.y); o.z = f2bf(v.z); o.w = f2bf(v.w);
    ((ushort4*)out)[i] = o;
  }
}

// ------------- transpose + convert: W[K][N] fp32 -> Wt[N][K] bf16 -------------
__global__ __launch_bounds__(256) void k_transpose(const float* __restrict__ W,
                                                   u16* __restrict__ Wt, int K, int N) {
  __shared__ u16 t[64][65];
  int k0 = blockIdx.y * 64, n0 = blockIdx.x * 64;
  int tx = threadIdx.x & 63, ty = threadIdx.x >> 6;
  for (int i = ty; i < 64; i += 4)
    t[i][tx] = f2bf(W[(size_t)(k0 + i) * N + n0 + tx]);
  __syncthreads();
  for (int i = ty; i < 64; i += 4)
    Wt[(size_t)(n0 + i) * K + k0 + tx] = t[tx][i];
}

// ------------- bf16 GEMM, A[M][K] @ Bt[N][K]^T, m97 structure -------------
template <int MODE>
__global__ __launch_bounds__(256) void k_gemm(const u16* __restrict__ A, const u16* __restrict__ Bt,
                                              const float* __restrict__ bias,
                                              u16* __restrict__ out_bf, float* __restrict__ out_f,
                                              u16* __restrict__ vt, int M, int N, int K) {
  __shared__ u16 lds_a[128 * 32];
  __shared__ u16 lds_b[128 * 32];
  const int lane = threadIdx.x & 63;
  const int wave = threadIdx.x >> 6;
  const int wm = wave & 1, wn = wave >> 1;
  const int row0 = blockIdx.y * 128;
  const int col0 = blockIdx.x * 128;
  f32x4 acc[4][4] = {};
  const int lr = lane >> 2;
  const int lc = (lane & 3) * 8;
  const u16* ga = A + (size_t)(row0 + wave * 32 + lr) * K + lc;
  const u16* gb = Bt + (size_t)(col0 + wave * 32 + lr) * K + lc;
  u16* la = lds_a + wave * 1024;
  u16* lb = lds_b + wave * 1024;
  const int fr = lane & 15, fk = (lane >> 4) * 8;

  for (int k0 = 0; k0 < K; k0 += 32) {
    __syncthreads();
    gl_lds16(ga + k0, la);
    gl_lds16(ga + 16 * K + k0, la + 512);
    gl_lds16(gb + k0, lb);
    gl_lds16(gb + 16 * K + k0, lb + 512);
    __syncthreads();
    b8 af[4], bfr[4];
#pragma unroll
    for (int i = 0; i < 4; ++i) af[i] = *(const b8*)&lds_a[(wm * 64 + i * 16 + fr) * 32 + fk];
#pragma unroll
    for (int i = 0; i < 4; ++i) bfr[i] = *(const b8*)&lds_b[(wn * 64 + i * 16 + fr) * 32 + fk];
#pragma unroll
    for (int mi = 0; mi < 4; ++mi)
#pragma unroll
      for (int ni = 0; ni < 4; ++ni)
        acc[mi][ni] = __builtin_amdgcn_mfma_f32_16x16x32_bf16(af[mi], bfr[ni], acc[mi][ni], 0, 0, 0);
  }

  const int fg = lane >> 4;
#pragma unroll
  for (int ni = 0; ni < 4; ++ni) {
    int col = col0 + wn * 64 + ni * 16 + fr;
    float bv = bias[col];
#pragma unroll
    for (int mi = 0; mi < 4; ++mi) {
#pragma unroll
      for (int r = 0; r < 4; ++r) {
        int row = row0 + wm * 64 + mi * 16 + fg * 4 + r;
        float v = acc[mi][ni][r] + bv;
        if (MODE == 0) {
          if (col < CEMB) {
            out_bf[(size_t)row * (2 * CEMB) + col] = f2bf(v * Q_PRESCALE);
          } else if (col < 2 * CEMB) {
            out_bf[(size_t)row * (2 * CEMB) + col] = f2bf(v);
          } else {
            int hd = col - 2 * CEMB;
            vt[((size_t)((row >> 11) * (NH * HD) + hd)) * T_SEQ + (row & (T_SEQ - 1))] = f2bf(v);
          }
        } else {
          out_f[(size_t)row * N + col] = v;
        }
      }
    }
  }
}

// ------------- causal flash attention: swapped-QK, QBLK=32/wave, KVBLK=64 -------------
// qk: [B*T][2048] bf16 (q cols 0..1023 pre-scaled to log2 units, k cols 1024..2047)
// vtg: [B*H*64][T] bf16 (V transposed)
// y : [B*T][1024] bf16
// Swapped QK: s = mfma(K_frag, Q_frag) -> lane c owns score row for q=c.
// Each wave owns 32 q rows as two 16-row subtiles at +wave*16 and +64+wave*16
// (all waves share the same causal boundary -> uniform trip count 2tt+2).
__global__ __launch_bounds__(256) void k_attn(const u16* __restrict__ qk,
                                              const u16* __restrict__ vtg,
                                              u16* __restrict__ y) {
  __shared__ __align__(16) u16 kt_s[2][64 * 64];
  __shared__ __align__(16) u16 vt_s[2][64 * 64];
  __shared__ __align__(16) char pl_s[4][4096];  // per-wave P: [2 subtiles][16 q][64 k] bf16

  const int lane = threadIdx.x & 63;
  const int wave = threadIdx.x >> 6;
  const int tid = threadIdx.x;
  const int g = lane >> 4, c = lane & 15;

  // Balanced XCD-chunked schedule over 1024 blocks (64 bh x 16 tiles of 128 q-rows).
  // Per XCD: 128 blocks in 4 groups of 32; CU j's tiles alternate (t, 15-t) -> uniform 68 iters.
  const int orig = blockIdx.x;
  const int xcd = orig & 7;
  const int s_in = orig >> 3;       // 0..127
  const int j = s_in & 31;
  const int gi = s_in >> 5;         // 0..3
  const int bh = xcd * 8 + gi * 2 + (j >> 4);
  const int tloc = j & 15;
  const int tt = ((gi ^ (j >> 4)) & 1) ? tloc : (15 - tloc);
  const int b = bh >> 4, h = bh & 15;
  const int qA = tt * 128 + wave * 16;  // subtile A q-base
  const int qB = qA + 64;               // subtile B q-base

  char* plw = pl_s[wave];

  // Q fragments (B-operand: col=lane&15=c -> q, k-dim=(lane>>4)*8+e -> d)
  const u16* qrowA = qk + (size_t)(b * T_SEQ + qA + c) * (2 * CEMB) + h * HD + g * 8;
  const b8 qfA0 = *(const b8*)qrowA;
  const b8 qfA1 = *(const b8*)(qrowA + 32);
  const u16* qrowB = qrowA + (size_t)64 * (2 * CEMB);
  const b8 qfB0 = *(const b8*)qrowB;
  const b8 qfB1 = *(const b8*)(qrowB + 32);

  // ones B-frag (col 0) -> denominator accumulates in o4 col 0 via matrix pipe
  b8 ones_frag;
#pragma unroll
  for (int e = 0; e < 8; ++e) ones_frag[e] = (c == 0) ? (__bf16)1.0f : (__bf16)0.0f;

  // staging source addressing (pre-swizzled global source, linear LDS dest)
  const int srow = tid >> 3;
  const int scc = (tid & 7) ^ (srow & 7);
  const u16* ksrc0 = qk + ((size_t)(b * T_SEQ) + srow) * (2 * CEMB) + CEMB + h * HD + scc * 8;
  const u16* vsrc0 = vtg + ((size_t)(bh * HD) + srow) * T_SEQ + scc * 8;

  float mA = -3e38f, mB = -3e38f;
  f32x4 oA[4] = {}, oB[4] = {};
  f32x4 o4A = {0.f, 0.f, 0.f, 0.f}, o4B = {0.f, 0.f, 0.f, 0.f};

  const int nt_tiles = 2 * tt + 2;

#define STAGE(t, bb)                                                    \
  {                                                                     \
    const u16* ks_ = ksrc0 + (size_t)(t) * 64 * (2 * CEMB);             \
    const u16* vs_ = vsrc0 + (t) * 64;                                  \
    gl_lds16(ks_, &kt_s[bb][wave * 512]);                               \
    gl_lds16(ks_ + 32 * (2 * CEMB), &kt_s[bb][wave * 512 + 2048]);      \
    gl_lds16(vs_, &vt_s[bb][wave * 512]);                               \
    gl_lds16(vs_ + 32 * T_SEQ, &vt_s[bb][wave * 512 + 2048]);           \
  }

  STAGE(0, 0);
  __syncthreads();

  int cur = 0;
  for (int t = 0; t < nt_tiles; ++t) {
    if (t + 1 < nt_tiles) STAGE(t + 1, cur ^ 1);
    const int k0 = t * 64;
    const bool lastt = (t == nt_tiles - 1);  // A fully masked -> skipped; B diagonal
    const bool sndl = (t == nt_tiles - 2);   // A diagonal; B fully below diagonal
    const u16* kt = kt_s[cur];
    const u16* vtl = vt_s[cur];

    // QK^T (swapped): s[n][r] = S[k=k0+n*16+g*4+r][q=c]
    f32x4 sA[4] = {{0.f,0.f,0.f,0.f},{0.f,0.f,0.f,0.f},{0.f,0.f,0.f,0.f},{0.f,0.f,0.f,0.f}};
    f32x4 sB[4] = {{0.f,0.f,0.f,0.f},{0.f,0.f,0.f,0.f},{0.f,0.f,0.f,0.f},{0.f,0.f,0.f,0.f}};
#pragma unroll
    for (int n = 0; n < 4; ++n) {
      const bool needA = (!lastt) && (!sndl || n <= wave);
      const bool needB = (!lastt) || (n <= wave);
      if (needA || needB) {
        const b8 kf0 = *(const b8*)&kt[(n * 16 + c) * 64 + ((g ^ (c & 7)) << 3)];
        const b8 kf1 = *(const b8*)&kt[(n * 16 + c) * 64 + (((4 + g) ^ (c & 7)) << 3)];
        if (needA) {
          sA[n] = __builtin_amdgcn_mfma_f32_16x16x32_bf16(kf0, qfA0, sA[n], 0, 0, 0);
          sA[n] = __builtin_amdgcn_mfma_f32_16x16x32_bf16(kf1, qfA1, sA[n], 0, 0, 0);
        }
        if (needB) {
          sB[n] = __builtin_amdgcn_mfma_f32_16x16x32_bf16(kf0, qfB0, sB[n], 0, 0, 0);
          sB[n] = __builtin_amdgcn_mfma_f32_16x16x32_bf16(kf1, qfB1, sB[n], 0, 0, 0);
        }
      }
    }

    // causal mask (k > q), only on the relevant diagonal tiles
    if (sndl) {
#pragma unroll
      for (int n = 0; n < 4; ++n)
#pragma unroll
        for (int r = 0; r < 4; ++r)
          if (k0 + n * 16 + g * 4 + r > qA + c) sA[n][r] = -3e38f;
    }
    if (lastt) {
#pragma unroll
      for (int n = 0; n < 4; ++n)
#pragma unroll
        for (int r = 0; r < 4; ++r)
          if (k0 + n * 16 + g * 4 + r > qB + c) sB[n][r] = -3e38f;
    }

    // row max: in-lane over 16 values + 2 cross-g shuffles (q=c is lane-local)
    float rmA = -3e38f, rmB = -3e38f;
    if (!lastt) {
#pragma unroll
      for (int n = 0; n < 4; ++n)
#pragma unroll
        for (int r = 0; r < 4; ++r) rmA = fmaxf(rmA, sA[n][r]);
      rmA = fmaxf(rmA, __shfl_xor(rmA, 16));
      rmA = fmaxf(rmA, __shfl_xor(rmA, 32));
    }
#pragma unroll
    for (int n = 0; n < 4; ++n)
#pragma unroll
      for (int r = 0; r < 4; ++r) rmB = fmaxf(rmB, sB[n][r]);
    rmB = fmaxf(rmB, __shfl_xor(rmB, 16));
    rmB = fmaxf(rmB, __shfl_xor(rmB, 32));

    // defer-max: rescale only when some row max grew by > 8 (P bounded by 2^8)
    bool ok = (lastt || rmA <= mA + 8.0f) && (rmB <= mB + 8.0f);
    if (!__all(ok)) {
      float alA = 1.0f, alB;
      if (!lastt) {
        float mn = fmaxf(mA, rmA);
        alA = __builtin_amdgcn_exp2f(mA - mn);
        mA = mn;
      }
      {
        float mn = fmaxf(mB, rmB);
        alB = __builtin_amdgcn_exp2f(mB - mn);
        mB = mn;
      }
      // o rows are q=g*4+r; alpha lives at lane c=q -> fetch via shuffle
#pragma unroll
      for (int r = 0; r < 4; ++r) {
        int src = (lane & 48) + g * 4 + r;
        float aA = __shfl(alA, src);
        float aB = __shfl(alB, src);
#pragma unroll
        for (int nt = 0; nt < 4; ++nt) { oA[nt][r] *= aA; oB[nt][r] *= aB; }
        o4A[r] *= aA; o4B[r] *= aB;
      }
    }

    // P = exp2(s - m); 4 consecutive k in-lane -> pack + one ds_write_b64 per n
    // swizzle: 8B chunk (n*4+g) ^ ((q&7)<<1) within row q=c
    if (!lastt) {
#pragma unroll
      for (int n = 0; n < 4; ++n) {
        u32 lo = pk2bf(__builtin_amdgcn_exp2f(sA[n][0] - mA),
                       __builtin_amdgcn_exp2f(sA[n][1] - mA));
        u32 hi = pk2bf(__builtin_amdgcn_exp2f(sA[n][2] - mA),
                       __builtin_amdgcn_exp2f(sA[n][3] - mA));
        *(u64*)(plw + c * 128 + (((n * 4 + g) ^ ((c & 7) << 1)) << 3)) =
            ((u64)hi << 32) | lo;
      }
    }
#pragma unroll
    for (int n = 0; n < 4; ++n) {
      u32 lo = pk2bf(__builtin_amdgcn_exp2f(sB[n][0] - mB),
                     __builtin_amdgcn_exp2f(sB[n][1] - mB));
      u32 hi = pk2bf(__builtin_amdgcn_exp2f(sB[n][2] - mB),
                     __builtin_amdgcn_exp2f(sB[n][3] - mB));
      *(u64*)(plw + 2048 + c * 128 + (((n * 4 + g) ^ ((c & 7) << 1)) << 3)) =
          ((u64)hi << 32) | lo;
    }
    asm volatile("s_waitcnt lgkmcnt(0)" ::: "memory");
    __builtin_amdgcn_sched_barrier(0);

    // PV: A-frag rows q=c -> read b128 with same chunk swizzle; V-frag shared
#pragma unroll
    for (int ks = 0; ks < 2; ++ks) {
      const int rdoff = c * 128 + ((((ks * 8 + 2 * g)) ^ ((c & 7) << 1)) << 3);
      b8 paA = {};
      if (!lastt) paA = *(const b8*)(plw + rdoff);
      const b8 paB = *(const b8*)(plw + 2048 + rdoff);
      if (!lastt) o4A = __builtin_amdgcn_mfma_f32_16x16x32_bf16(paA, ones_frag, o4A, 0, 0, 0);
      o4B = __builtin_amdgcn_mfma_f32_16x16x32_bf16(paB, ones_frag, o4B, 0, 0, 0);
#pragma unroll
      for (int nt = 0; nt < 4; ++nt) {
        const b8 vb = *(const b8*)&vtl[(nt * 16 + c) * 64 + (((ks * 4 + g) ^ (c & 7)) << 3)];
        if (!lastt) oA[nt] = __builtin_amdgcn_mfma_f32_16x16x32_bf16(paA, vb, oA[nt], 0, 0, 0);
        oB[nt] = __builtin_amdgcn_mfma_f32_16x16x32_bf16(paB, vb, oB[nt], 0, 0, 0);
      }
    }

    __syncthreads();
    cur ^= 1;
  }
#undef STAGE

  // denominator in col 0 (lanes c==0 of each g-group)
#pragma unroll
  for (int r = 0; r < 4; ++r) {
    float lA = __shfl(o4A[r], lane & 48);
    float lB = __shfl(o4B[r], lane & 48);
    float invA = 1.0f / lA;
    float invB = 1.0f / lB;
#pragma unroll
    for (int nt = 0; nt < 4; ++nt) {
      __bf16 va = (__bf16)(oA[nt][r] * invA);
      __bf16 vb = (__bf16)(oB[nt][r] * invB);
      y[(size_t)(b * T_SEQ + qA + g * 4 + r) * CEMB + h * HD + nt * 16 + c] = *(u16*)&va;
      y[(size_t)(b * T_SEQ + qB + g * 4 + r) * CEMB + h * HD + nt * 16 + c] = *(u16*)&vb;
    }
  }
}

extern "C" void kernel_launch(void* const* d_in, const int* in_sizes, int n_in,
                              void* d_out, int out_size, void* d_ws, size_t ws_size,
                              hipStream_t stream) {
  const float* x = (const float*)d_in[0];
  const float* W_attn = (const float*)d_in[1];
  const float* b_attn = (const float*)d_in[2];
  const float* W_proj = (const float*)d_in[3];
  const float* b_proj = (const float*)d_in[4];
  float* out = (float*)d_out;

  char* ws = (char*)d_ws;
  u16* x_bf    = (u16*)(ws);
  u16* wattn_t = (u16*)(ws + 16777216);
  u16* wproj_t = (u16*)(ws + 23068672);
  u16* qk_bf   = (u16*)(ws + 25165824);
  u16* vt      = (u16*)(ws + 58720256);
  u16* y_bf    = (u16*)(ws + 75497472);

  k_convert<<<2048, 256, 0, stream>>>(x, x_bf, (NB * T_SEQ * CEMB) / 4);
  k_transpose<<<dim3(3 * CEMB / 64, CEMB / 64), 256, 0, stream>>>(W_attn, wattn_t, CEMB, 3 * CEMB);
  k_transpose<<<dim3(CEMB / 64, CEMB / 64), 256, 0, stream>>>(W_proj, wproj_t, CEMB, CEMB);
  k_gemm<0><<<dim3(3 * CEMB / 128, M_ROWS / 128), 256, 0, stream>>>(
      x_bf, wattn_t, b_attn, qk_bf, nullptr, vt, M_ROWS, 3 * CEMB, CEMB);
  k_attn<<<1024, 256, 0, stream>>>(qk_bf, vt, y_bf);
  k_gemm<1><<<dim3(CEMB / 128, M_ROWS / 128), 256, 0, stream>>>(
      y_bf, wproj_t, b_proj, nullptr, out, nullptr, M_ROWS, CEMB, CEMB);
}

// Round 5
// 219.205 us; speedup vs baseline: 2.7186x; 1.1043x over previous
//
#include <hip/hip_runtime.h>

typedef unsigned short u16;
typedef unsigned int u32;
typedef unsigned long long u64;
typedef __attribute__((ext_vector_type(8))) __bf16 b8;
typedef __attribute__((ext_vector_type(4))) float f32x4;

#define T_SEQ 2048
#define NB 4
#define NH 16
#define HD 64
#define CEMB 1024
#define M_ROWS (NB * T_SEQ)  // 8192
// 0.125 * log2(e): folds softmax scale AND exp->exp2 conversion into Q
#define Q_PRESCALE 0.18033688011112042f

__device__ __forceinline__ u16 f2bf(float f) {
  union { float f; unsigned int u; } v; v.f = f;
  unsigned int r = v.u + 0x7FFFu + ((v.u >> 16) & 1u);
  return (u16)(r >> 16);
}

__device__ __forceinline__ u32 pk2bf(float a, float b) {
  __bf16 x = (__bf16)a, y = (__bf16)b;
  return (u32)*(u16*)&x | ((u32)*(u16*)&y << 16);
}

__device__ __forceinline__ void gl_lds16(const u16* g, u16* l) {
  __builtin_amdgcn_global_load_lds(
      (const __attribute__((address_space(1))) unsigned int*)g,
      (__attribute__((address_space(3))) unsigned int*)l, 16, 0, 0);
}

// ---------------- convert fp32 -> bf16 (vectorized) ----------------
__global__ void k_convert(const float* __restrict__ in, u16* __restrict__ out, int n4) {
  int i = blockIdx.x * blockDim.x + threadIdx.x;
  int stride = gridDim.x * blockDim.x;
  for (; i < n4; i += stride) {
    float4 v = ((const float4*)in)[i];
    ushort4 o;
    o.x = f2bf(v.x); o.y = f2bf(v.y); o.z = f2bf(v.z); o.w = f2bf(v.w);
    ((ushort4*)out)[i] = o;
  }
}

// ------------- transpose + convert: W[K][N] fp32 -> Wt[N][K] bf16 -------------
__global__ __launch_bounds__(256) void k_transpose(const float* __restrict__ W,
                                                   u16* __restrict__ Wt, int K, int N) {
  __shared__ u16 t[64][65];
  int k0 = blockIdx.y * 64, n0 = blockIdx.x * 64;
  int tx = threadIdx.x & 63, ty = threadIdx.x >> 6;
  for (int i = ty; i < 64; i += 4)
    t[i][tx] = f2bf(W[(size_t)(k0 + i) * N + n0 + tx]);
  __syncthreads();
  for (int i = ty; i < 64; i += 4)
    Wt[(size_t)(n0 + i) * K + k0 + tx] = t[tx][i];
}

// ------------- bf16 GEMM, A[M][K] @ Bt[N][K]^T, m97 structure -------------
template <int MODE>
__global__ __launch_bounds__(256) void k_gemm(const u16* __restrict__ A, const u16* __restrict__ Bt,
                                              const float* __restrict__ bias,
                                              u16* __restrict__ out_bf, float* __restrict__ out_f,
                                              u16* __restrict__ vt, int M, int N, int K) {
  __shared__ u16 lds_a[128 * 32];
  __shared__ u16 lds_b[128 * 32];
  const int lane = threadIdx.x & 63;
  const int wave = threadIdx.x >> 6;
  const int wm = wave & 1, wn = wave >> 1;
  const int row0 = blockIdx.y * 128;
  const int col0 = blockIdx.x * 128;
  f32x4 acc[4][4] = {};
  const int lr = lane >> 2;
  const int lc = (lane & 3) * 8;
  const u16* ga = A + (size_t)(row0 + wave * 32 + lr) * K + lc;
  const u16* gb = Bt + (size_t)(col0 + wave * 32 + lr) * K + lc;
  u16* la = lds_a + wave * 1024;
  u16* lb = lds_b + wave * 1024;
  const int fr = lane & 15, fk = (lane >> 4) * 8;

  for (int k0 = 0; k0 < K; k0 += 32) {
    __syncthreads();
    gl_lds16(ga + k0, la);
    gl_lds16(ga + 16 * K + k0, la + 512);
    gl_lds16(gb + k0, lb);
    gl_lds16(gb + 16 * K + k0, lb + 512);
    __syncthreads();
    b8 af[4], bfr[4];
#pragma unroll
    for (int i = 0; i < 4; ++i) af[i] = *(const b8*)&lds_a[(wm * 64 + i * 16 + fr) * 32 + fk];
#pragma unroll
    for (int i = 0; i < 4; ++i) bfr[i] = *(const b8*)&lds_b[(wn * 64 + i * 16 + fr) * 32 + fk];
#pragma unroll
    for (int mi = 0; mi < 4; ++mi)
#pragma unroll
      for (int ni = 0; ni < 4; ++ni)
        acc[mi][ni] = __builtin_amdgcn_mfma_f32_16x16x32_bf16(af[mi], bfr[ni], acc[mi][ni], 0, 0, 0);
  }

  const int fg = lane >> 4;
#pragma unroll
  for (int ni = 0; ni < 4; ++ni) {
    int col = col0 + wn * 64 + ni * 16 + fr;
    float bv = bias[col];
#pragma unroll
    for (int mi = 0; mi < 4; ++mi) {
#pragma unroll
      for (int r = 0; r < 4; ++r) {
        int row = row0 + wm * 64 + mi * 16 + fg * 4 + r;
        float v = acc[mi][ni][r] + bv;
        if (MODE == 0) {
          if (col < CEMB) {
            out_bf[(size_t)row * (2 * CEMB) + col] = f2bf(v * Q_PRESCALE);
          } else if (col < 2 * CEMB) {
            out_bf[(size_t)row * (2 * CEMB) + col] = f2bf(v);
          } else {
            int hd = col - 2 * CEMB;
            vt[((size_t)((row >> 11) * (NH * HD) + hd)) * T_SEQ + (row & (T_SEQ - 1))] = f2bf(v);
          }
        } else {
          out_f[(size_t)row * N + col] = v;
        }
      }
    }
  }
}

// ------------- causal flash attention: swapped-QK, QBLK=32/wave, KVBLK=64 -------------
// qk: [B*T][2048] bf16 (q cols 0..1023 pre-scaled to log2 units, k cols 1024..2047)
// vtg: [B*H*64][T] bf16 (V transposed)
// y : [B*T][1024] bf16
// LDS 40KB -> 4 blocks/CU, entire 1024-block grid co-resident.
// A/B subtiles time-share one 2KB/wave P buffer (per-wave LDS ops are in-order).
__global__ __launch_bounds__(256) void k_attn(const u16* __restrict__ qk,
                                              const u16* __restrict__ vtg,
                                              u16* __restrict__ y) {
  __shared__ __align__(16) u16 kt_s[2][64 * 64];
  __shared__ __align__(16) u16 vt_s[2][64 * 64];
  __shared__ __align__(16) char pl_s[4][2048];  // per-wave P: [16 q][64 k] bf16 (shared A/B)

  const int lane = threadIdx.x & 63;
  const int wave = threadIdx.x >> 6;
  const int tid = threadIdx.x;
  const int g = lane >> 4, c = lane & 15;

  // Schedule: xcd = orig&7 (8 heads per XCD -> 4MB KV working set, L2-resident).
  // rank-outer order, tt permutation {15..12, 8..11, 7..4, 0..3}: longest blocks
  // dispatch first AND under round-robin fill each CU's 4 blocks sum to 68 iters.
  const int orig = blockIdx.x;
  const int xcd = orig & 7;
  const int idx = orig >> 3;        // 0..127 within XCD
  const int ri = idx >> 3;          // 0..15 dispatch rank
  const int hh = idx & 7;
  const int bh = xcd * 8 + hh;
  const int tt = (ri & 4) ? ((ri & 8) ? ri - 12 : ri + 4) : (15 - ri);
  const int b = bh >> 4, h = bh & 15;
  const int qA = tt * 128 + wave * 16;  // subtile A q-base
  const int qB = qA + 64;               // subtile B q-base

  char* plw = pl_s[wave];
  char* plA = plw + c * 128;  // this lane's P row (q=c)
  const int b3 = c >> 3;
  const int e2 = (c & 7) << 1;
  const int sb = g + b3 * 8;  // store slot bias

  // Q fragments (B-operand: col=lane&15=c -> q, k-dim=(lane>>4)*8+e -> d)
  const u16* qrowA = qk + (size_t)(b * T_SEQ + qA + c) * (2 * CEMB) + h * HD + g * 8;
  const b8 qfA0 = *(const b8*)qrowA;
  const b8 qfA1 = *(const b8*)(qrowA + 32);
  const u16* qrowB = qrowA + (size_t)64 * (2 * CEMB);
  const b8 qfB0 = *(const b8*)qrowB;
  const b8 qfB1 = *(const b8*)(qrowB + 32);

  // ones B-frag (col 0) -> denominator accumulates in o4 col 0 via matrix pipe
  b8 ones_frag;
#pragma unroll
  for (int e = 0; e < 8; ++e) ones_frag[e] = (c == 0) ? (__bf16)1.0f : (__bf16)0.0f;

  // staging source addressing (pre-swizzled global source, linear LDS dest)
  const int srow = tid >> 3;
  const int scc = (tid & 7) ^ (srow & 7);
  const u16* ksrc0 = qk + ((size_t)(b * T_SEQ) + srow) * (2 * CEMB) + CEMB + h * HD + scc * 8;
  const u16* vsrc0 = vtg + ((size_t)(bh * HD) + srow) * T_SEQ + scc * 8;

  float mA = -3e38f, mB = -3e38f;
  f32x4 oA[4] = {}, oB[4] = {};
  f32x4 o4A = {0.f, 0.f, 0.f, 0.f}, o4B = {0.f, 0.f, 0.f, 0.f};

  const int nt_tiles = 2 * tt + 2;

#define STAGE(t, bb)                                                    \
  {                                                                     \
    const u16* ks_ = ksrc0 + (size_t)(t) * 64 * (2 * CEMB);             \
    const u16* vs_ = vsrc0 + (t) * 64;                                  \
    gl_lds16(ks_, &kt_s[bb][wave * 512]);                               \
    gl_lds16(ks_ + 32 * (2 * CEMB), &kt_s[bb][wave * 512 + 2048]);      \
    gl_lds16(vs_, &vt_s[bb][wave * 512]);                               \
    gl_lds16(vs_ + 32 * T_SEQ, &vt_s[bb][wave * 512 + 2048]);           \
  }

  STAGE(0, 0);
  __syncthreads();

  int cur = 0;
  for (int t = 0; t < nt_tiles; ++t) {
    if (t + 1 < nt_tiles) STAGE(t + 1, cur ^ 1);
    const int k0 = t * 64;
    const bool lastt = (t == nt_tiles - 1);  // A fully masked -> skipped; B diagonal
    const bool sndl = (t == nt_tiles - 2);   // A diagonal
    const u16* kt = kt_s[cur];
    const u16* vtl = vt_s[cur];

    // QK^T (swapped): s[n][r] = S[k=k0+n*16+g*4+r][q=c]
    f32x4 sA[4] = {{0.f,0.f,0.f,0.f},{0.f,0.f,0.f,0.f},{0.f,0.f,0.f,0.f},{0.f,0.f,0.f,0.f}};
    f32x4 sB[4] = {{0.f,0.f,0.f,0.f},{0.f,0.f,0.f,0.f},{0.f,0.f,0.f,0.f},{0.f,0.f,0.f,0.f}};
    __builtin_amdgcn_s_setprio(1);
#pragma unroll
    for (int n = 0; n < 4; ++n) {
      const bool needA = (!lastt) && (!sndl || n <= wave);
      const bool needB = (!lastt) || (n <= wave);
      if (needA || needB) {
        const b8 kf0 = *(const b8*)&kt[(n * 16 + c) * 64 + ((g ^ (c & 7)) << 3)];
        const b8 kf1 = *(const b8*)&kt[(n * 16 + c) * 64 + (((4 + g) ^ (c & 7)) << 3)];
        if (needA) {
          sA[n] = __builtin_amdgcn_mfma_f32_16x16x32_bf16(kf0, qfA0, sA[n], 0, 0, 0);
          sA[n] = __builtin_amdgcn_mfma_f32_16x16x32_bf16(kf1, qfA1, sA[n], 0, 0, 0);
        }
        if (needB) {
          sB[n] = __builtin_amdgcn_mfma_f32_16x16x32_bf16(kf0, qfB0, sB[n], 0, 0, 0);
          sB[n] = __builtin_amdgcn_mfma_f32_16x16x32_bf16(kf1, qfB1, sB[n], 0, 0, 0);
        }
      }
    }
    __builtin_amdgcn_s_setprio(0);

    // causal mask (k > q), only on the relevant diagonal tiles
    if (sndl) {
#pragma unroll
      for (int n = 0; n < 4; ++n)
#pragma unroll
        for (int r = 0; r < 4; ++r)
          if (k0 + n * 16 + g * 4 + r > qA + c) sA[n][r] = -3e38f;
    }
    if (lastt) {
#pragma unroll
      for (int n = 0; n < 4; ++n)
#pragma unroll
        for (int r = 0; r < 4; ++r)
          if (k0 + n * 16 + g * 4 + r > qB + c) sB[n][r] = -3e38f;
    }

    // row max: in-lane over 16 values + 2 cross-g shuffles (q=c is lane-local)
    float rmA = -3e38f, rmB = -3e38f;
    if (!lastt) {
#pragma unroll
      for (int n = 0; n < 4; ++n)
#pragma unroll
        for (int r = 0; r < 4; ++r) rmA = fmaxf(rmA, sA[n][r]);
      rmA = fmaxf(rmA, __shfl_xor(rmA, 16));
      rmA = fmaxf(rmA, __shfl_xor(rmA, 32));
    }
#pragma unroll
    for (int n = 0; n < 4; ++n)
#pragma unroll
      for (int r = 0; r < 4; ++r) rmB = fmaxf(rmB, sB[n][r]);
    rmB = fmaxf(rmB, __shfl_xor(rmB, 16));
    rmB = fmaxf(rmB, __shfl_xor(rmB, 32));

    // defer-max: rescale only when some row max grew by > 8 (P bounded by 2^8)
    bool ok = (lastt || rmA <= mA + 8.0f) && (rmB <= mB + 8.0f);
    if (!__all(ok)) {
      float alA = 1.0f, alB;
      if (!lastt) {
        float mn = fmaxf(mA, rmA);
        alA = __builtin_amdgcn_exp2f(mA - mn);
        mA = mn;
      }
      {
        float mn = fmaxf(mB, rmB);
        alB = __builtin_amdgcn_exp2f(mB - mn);
        mB = mn;
      }
#pragma unroll
      for (int r = 0; r < 4; ++r) {
        int src = (lane & 48) + g * 4 + r;
        float aA = __shfl(alA, src);
        float aB = __shfl(alB, src);
#pragma unroll
        for (int nt = 0; nt < 4; ++nt) { oA[nt][r] *= aA; oB[nt][r] *= aB; }
        o4A[r] *= aA; o4B[r] *= aB;
      }
    }

    // pack P (bf16 pairs); store A now, keep B packed in regs until PV_A reads done.
    // conflict-free slot: sigma(kc,c) = ((kc + 8*(c>>3)) & 15) ^ (2*(c&7))
    if (!lastt) {
#pragma unroll
      for (int n = 0; n < 4; ++n) {
        u32 lo = pk2bf(__builtin_amdgcn_exp2f(sA[n][0] - mA),
                       __builtin_amdgcn_exp2f(sA[n][1] - mA));
        u32 hi = pk2bf(__builtin_amdgcn_exp2f(sA[n][2] - mA),
                       __builtin_amdgcn_exp2f(sA[n][3] - mA));
        *(u64*)(plA + ((((4 * n + sb) & 15) ^ e2) << 3)) = ((u64)hi << 32) | lo;
      }
    }
    u64 pbB[4];
#pragma unroll
    for (int n = 0; n < 4; ++n) {
      u32 lo = pk2bf(__builtin_amdgcn_exp2f(sB[n][0] - mB),
                     __builtin_amdgcn_exp2f(sB[n][1] - mB));
      u32 hi = pk2bf(__builtin_amdgcn_exp2f(sB[n][2] - mB),
                     __builtin_amdgcn_exp2f(sB[n][3] - mB));
      pbB[n] = ((u64)hi << 32) | lo;
    }

    // V fragments preloaded once, reused by PV_A and PV_B
    b8 vb[2][4];
#pragma unroll
    for (int ks = 0; ks < 2; ++ks)
#pragma unroll
      for (int nt = 0; nt < 4; ++nt)
        vb[ks][nt] = *(const b8*)&vtl[(nt * 16 + c) * 64 + (((ks * 4 + g) ^ (c & 7)) << 3)];

    asm volatile("s_waitcnt lgkmcnt(0)" ::: "memory");
    __builtin_amdgcn_sched_barrier(0);

    // PV_A (per-wave LDS in-order: later P_B writes cannot pass these reads)
    if (!lastt) {
      __builtin_amdgcn_s_setprio(1);
#pragma unroll
      for (int ks = 0; ks < 2; ++ks) {
        const b8 paA = *(const b8*)(plA + ((((ks * 8 + 2 * g + 8 * b3) & 15) ^ e2) << 3));
        o4A = __builtin_amdgcn_mfma_f32_16x16x32_bf16(paA, ones_frag, o4A, 0, 0, 0);
#pragma unroll
        for (int nt = 0; nt < 4; ++nt)
          oA[nt] = __builtin_amdgcn_mfma_f32_16x16x32_bf16(paA, vb[ks][nt], oA[nt], 0, 0, 0);
      }
      __builtin_amdgcn_s_setprio(0);
    }

    // store packed P_B, then PV_B
#pragma unroll
    for (int n = 0; n < 4; ++n)
      *(u64*)(plA + ((((4 * n + sb) & 15) ^ e2) << 3)) = pbB[n];
    asm volatile("s_waitcnt lgkmcnt(0)" ::: "memory");
    __builtin_amdgcn_sched_barrier(0);

    __builtin_amdgcn_s_setprio(1);
#pragma unroll
    for (int ks = 0; ks < 2; ++ks) {
      const b8 paB = *(const b8*)(plA + ((((ks * 8 + 2 * g + 8 * b3) & 15) ^ e2) << 3));
      o4B = __builtin_amdgcn_mfma_f32_16x16x32_bf16(paB, ones_frag, o4B, 0, 0, 0);
#pragma unroll
      for (int nt = 0; nt < 4; ++nt)
        oB[nt] = __builtin_amdgcn_mfma_f32_16x16x32_bf16(paB, vb[ks][nt], oB[nt], 0, 0, 0);
    }
    __builtin_amdgcn_s_setprio(0);

    __syncthreads();
    cur ^= 1;
  }
#undef STAGE

  // denominator in col 0 (lanes c==0 of each g-group)
#pragma unroll
  for (int r = 0; r < 4; ++r) {
    float lA = __shfl(o4A[r], lane & 48);
    float lB = __shfl(o4B[r], lane & 48);
    float invA = 1.0f / lA;
    float invB = 1.0f / lB;
#pragma unroll
    for (int nt = 0; nt < 4; ++nt) {
      __bf16 va = (__bf16)(oA[nt][r] * invA);
      __bf16 vbv = (__bf16)(oB[nt][r] * invB);
      y[(size_t)(b * T_SEQ + qA + g * 4 + r) * CEMB + h * HD + nt * 16 + c] = *(u16*)&va;
      y[(size_t)(b * T_SEQ + qB + g * 4 + r) * CEMB + h * HD + nt * 16 + c] = *(u16*)&vbv;
    }
  }
}

extern "C" void kernel_launch(void* const* d_in, const int* in_sizes, int n_in,
                              void* d_out, int out_size, void* d_ws, size_t ws_size,
                              hipStream_t stream) {
  const float* x = (const float*)d_in[0];
  const float* W_attn = (const float*)d_in[1];
  const float* b_attn = (const float*)d_in[2];
  const float* W_proj = (const float*)d_in[3];
  const float* b_proj = (const float*)d_in[4];
  float* out = (float*)d_out;

  char* ws = (char*)d_ws;
  u16* x_bf    = (u16*)(ws);
  u16* wattn_t = (u16*)(ws + 16777216);
  u16* wproj_t = (u16*)(ws + 23068672);
  u16* qk_bf   = (u16*)(ws + 25165824);
  u16* vt      = (u16*)(ws + 58720256);
  u16* y_bf    = (u16*)(ws + 75497472);

  k_convert<<<2048, 256, 0, stream>>>(x, x_bf, (NB * T_SEQ * CEMB) / 4);
  k_transpose<<<dim3(3 * CEMB / 64, CEMB / 64), 256, 0, stream>>>(W_attn, wattn_t, CEMB, 3 * CEMB);
  k_transpose<<<dim3(CEMB / 64, CEMB / 64), 256, 0, stream>>>(W_proj, wproj_t, CEMB, CEMB);
  k_gemm<0><<<dim3(3 * CEMB / 128, M_ROWS / 128), 256, 0, stream>>>(
      x_bf, wattn_t, b_attn, qk_bf, nullptr, vt, M_ROWS, 3 * CEMB, CEMB);
  k_attn<<<1024, 256, 0, stream>>>(qk_bf, vt, y_bf);
  k_gemm<1><<<dim3(CEMB / 128, M_ROWS / 128), 256, 0, stream>>>(
      y_bf, wproj_t, b_proj, nullptr, out, nullptr, M_ROWS, CEMB, CEMB);
}